// Round 1
// baseline (106.901 us; speedup 1.0000x reference)
//
#include <hip/hip_runtime.h>

typedef short bf16x8 __attribute__((ext_vector_type(8)));
typedef float f32x4  __attribute__((ext_vector_type(4)));

__device__ __forceinline__ unsigned short f2bf_rne(float x) {
  union { float f; unsigned u; } a; a.f = x;
  unsigned r = a.u + 0x7fffu + ((a.u >> 16) & 1u);   // round-to-nearest-even
  return (unsigned short)(r >> 16);
}

// vec:[N][3] f32, sph:[3][512] f32, wts:[512][64] f32, sigma:[1] f32 -> out:[N][64] f32
__global__ __launch_bounds__(256, 2) void sph_enc_kernel(
    const float* __restrict__ vec,
    const float* __restrict__ sph,
    const float* __restrict__ wts,
    const float* __restrict__ sigp,
    float* __restrict__ out)
{
  // WT[c][k] bf16, c-major (1KB rows), XOR-swizzled byte^=(c&7)<<4 so that
  // 16 lanes reading 16 different c-rows at the same k-range spread across banks.
  __shared__ __align__(16) unsigned char wlds[64 * 512 * 2];   // 64 KB
  __shared__ __align__(16) float slds[3 * 512];                // 6 KB

  const int tid  = threadIdx.x;
  const int lane = tid & 63;
  const int wave = tid >> 6;

  // ---- stage sphere_pos (1536 f32, coalesced) ----
  #pragma unroll
  for (int i = 0; i < 6; ++i) slds[i * 256 + tid] = sph[i * 256 + tid];

  // ---- stage weights: [512][64] f32 -> bf16 WT[c][k] swizzled ----
  {
    const int c   = tid & 63;
    const int kb  = (tid >> 6) << 3;              // 0,8,16,24
    const int swz = (c & 7) << 4;
    #pragma unroll
    for (int pass = 0; pass < 16; ++pass) {
      const int k0 = pass * 32 + kb;
      unsigned pk[4];
      #pragma unroll
      for (int i = 0; i < 4; ++i) {
        const unsigned lo = f2bf_rne(wts[(k0 + 2 * i)     * 64 + c]);
        const unsigned hi = f2bf_rne(wts[(k0 + 2 * i + 1) * 64 + c]);
        pk[i] = lo | (hi << 16);
      }
      *reinterpret_cast<uint4*>(wlds + (((c << 10) + (k0 << 1)) ^ swz)) =
          make_uint4(pk[0], pk[1], pk[2], pk[3]);
    }
  }
  __syncthreads();

  const float sigma = sigp[0];
  // p = exp(-(ang/sigma)^2/2) / (SQ2PI*sigma) = exp(fma(ang^2, k1, k2))
  const float k1 = -0.5f / (sigma * sigma);
  const float k2 = -__logf(2.50662827463f * sigma);

  const int r16  = lane & 15;     // MFMA A-row / D-col index
  const int q    = lane >> 4;     // k-group
  const int grow = (blockIdx.x << 6) + (wave << 4) + r16;

  const float vx = vec[grow * 3 + 0];
  const float vy = vec[grow * 3 + 1];
  const float vz = vec[grow * 3 + 2];

  f32x4 acc[4];
  #pragma unroll
  for (int nb = 0; nb < 4; ++nb) acc[nb] = (f32x4){0.f, 0.f, 0.f, 0.f};
  float rsum = 0.0f;

  const int swz_r = (lane & 7) << 4;   // (c&7)==(lane&7) for every nb block

  #pragma unroll
  for (int kt = 0; kt < 16; ++kt) {
    const int j0 = kt * 32 + q * 8;    // this lane's 8 consecutive sphere indices

    float sx[8], sy[8], sz[8];
    {
      float4 t;
      t = *reinterpret_cast<const float4*>(&slds[j0]);
      sx[0]=t.x; sx[1]=t.y; sx[2]=t.z; sx[3]=t.w;
      t = *reinterpret_cast<const float4*>(&slds[j0 + 4]);
      sx[4]=t.x; sx[5]=t.y; sx[6]=t.z; sx[7]=t.w;
      t = *reinterpret_cast<const float4*>(&slds[512 + j0]);
      sy[0]=t.x; sy[1]=t.y; sy[2]=t.z; sy[3]=t.w;
      t = *reinterpret_cast<const float4*>(&slds[512 + j0 + 4]);
      sy[4]=t.x; sy[5]=t.y; sy[6]=t.z; sy[7]=t.w;
      t = *reinterpret_cast<const float4*>(&slds[1024 + j0]);
      sz[0]=t.x; sz[1]=t.y; sz[2]=t.z; sz[3]=t.w;
      t = *reinterpret_cast<const float4*>(&slds[1024 + j0 + 4]);
      sz[4]=t.x; sz[5]=t.y; sz[6]=t.z; sz[7]=t.w;
    }

    union { bf16x8 v; unsigned short u[8]; } af;
    #pragma unroll
    for (int e = 0; e < 8; ++e) {
      float d = fmaf(vx, sx[e], fmaf(vy, sy[e], vz * sz[e]));
      d = fminf(fmaxf(d, -0.99999f), 0.99999f);
      // acos(d)^2 = 2u * P(u), u = 1-d  (5-term series; exact where Gaussian matters)
      const float uu = 1.0f - d;
      float P = fmaf(uu, 0.00507936f, 0.01428571f);
      P = fmaf(uu, P, 0.04444444f);
      P = fmaf(uu, P, 0.16666667f);
      P = fmaf(uu, P, 1.0f);
      const float g  = (uu + uu) * P;
      const float pr = __expf(fmaf(g, k1, k2));
      rsum += pr;
      af.u[e] = f2bf_rne(pr);
    }

    const int kbyte = j0 << 1;
    #pragma unroll
    for (int nb = 0; nb < 4; ++nb) {
      const bf16x8 bf = *reinterpret_cast<const bf16x8*>(
          wlds + (((((nb << 4) + r16) << 10) + kbyte) ^ swz_r));
      acc[nb] = __builtin_amdgcn_mfma_f32_16x16x32_bf16(af.v, bf, acc[nb], 0, 0, 0);
    }
  }

  // full row-sum: lanes {l, l^16, l^32, l^48} share a row
  rsum += __shfl_xor(rsum, 16);
  rsum += __shfl_xor(rsum, 32);

  // C/D layout: col = lane&15, row = (lane>>4)*4 + reg
  #pragma unroll
  for (int reg = 0; reg < 4; ++reg) {
    const int orow = (q << 2) + reg;
    const float rs   = __shfl(rsum, orow);        // lane 'orow' holds row orow's sum
    const float rinv = 1.0f / (rs + 1e-8f);
    const int base = (((blockIdx.x << 6) + (wave << 4) + orow) << 6) + r16;
    out[base +  0] = acc[0][reg] * rinv;
    out[base + 16] = acc[1][reg] * rinv;
    out[base + 32] = acc[2][reg] * rinv;
    out[base + 48] = acc[3][reg] * rinv;
  }
}

extern "C" void kernel_launch(void* const* d_in, const int* in_sizes, int n_in,
                              void* d_out, int out_size, void* d_ws, size_t ws_size,
                              hipStream_t stream) {
  const float* vec = (const float*)d_in[0];
  const float* sph = (const float*)d_in[1];
  const float* wts = (const float*)d_in[2];
  const float* sig = (const float*)d_in[3];
  float* out = (float*)d_out;
  const int n      = in_sizes[0] / 3;   // 262144
  const int blocks = n >> 6;            // 64 rows per block
  hipLaunchKernelGGL(sph_enc_kernel, dim3(blocks), dim3(256), 0, stream,
                     vec, sph, wts, sig, out);
}

// Round 2
// 61.975 us; speedup vs baseline: 1.7249x; 1.7249x over previous
//
#include <hip/hip_runtime.h>

typedef short bf16x8 __attribute__((ext_vector_type(8)));
typedef float f32x4  __attribute__((ext_vector_type(4)));

__device__ __forceinline__ unsigned short f2bf_rne(float x) {
  union { float f; unsigned u; } a; a.f = x;
  unsigned r = a.u + 0x7fffu + ((a.u >> 16) & 1u);   // round-to-nearest-even
  return (unsigned short)(r >> 16);
}

__device__ __forceinline__ float fast_exp2(float x) {
#if __has_builtin(__builtin_amdgcn_exp2f)
  return __builtin_amdgcn_exp2f(x);
#else
  float r; asm("v_exp_f32 %0, %1" : "=v"(r) : "v"(x)); return r;
#endif
}

// vec:[N][3] f32, sph:[3][512] f32, wts:[512][64] f32, sigma:[1] f32 -> out:[N][64] f32
__global__ __launch_bounds__(512, 4) void sph_enc_kernel(
    const float* __restrict__ vec,
    const float* __restrict__ sph,
    const float* __restrict__ wts,
    const float* __restrict__ sigp,
    float* __restrict__ out)
{
  // WT[c][k] bf16, c-major (1KB rows), XOR-swizzled byte^=(c&7)<<4 so that
  // 16 lanes reading 16 different c-rows at the same k-range spread across banks.
  __shared__ __align__(16) unsigned char wlds[64 * 512 * 2];   // 64 KB
  __shared__ __align__(16) float slds[3 * 512];                // 6 KB

  const int tid  = threadIdx.x;
  const int lane = tid & 63;
  const int wave = tid >> 6;

  // ---- stage sphere_pos (1536 f32, coalesced; 512 threads x 3) ----
  #pragma unroll
  for (int i = 0; i < 3; ++i) slds[i * 512 + tid] = sph[i * 512 + tid];

  // ---- stage weights: [512][64] f32 -> bf16 WT[c][k] swizzled ----
  {
    const int c    = tid & 63;
    const int kgrp = tid >> 6;                    // 0..7
    const int swz  = (c & 7) << 4;
    #pragma unroll
    for (int pass = 0; pass < 8; ++pass) {
      const int k0 = pass * 64 + (kgrp << 3);
      unsigned pk[4];
      #pragma unroll
      for (int i = 0; i < 4; ++i) {
        const unsigned lo = f2bf_rne(wts[(k0 + 2 * i)     * 64 + c]);
        const unsigned hi = f2bf_rne(wts[(k0 + 2 * i + 1) * 64 + c]);
        pk[i] = lo | (hi << 16);
      }
      *reinterpret_cast<uint4*>(wlds + (((c << 10) + (k0 << 1)) ^ swz)) =
          make_uint4(pk[0], pk[1], pk[2], pk[3]);
    }
  }
  __syncthreads();

  const float sigma = sigp[0];
  // p = exp(-(ang^2)/(2 sigma^2)) / (SQ2PI*sigma);  ang^2 = 2u*P(u), u = 1-cos
  // in exp2 space: p = exp2( (u*P) * K1 + K2 )
  const float K1 = -1.44269504f / (sigma * sigma);          // 2 * (-0.5/s^2) * log2e
  const float K2 = -__log2f(2.50662827463f * sigma);

  const int r16  = lane & 15;     // MFMA A-row / D-col index
  const int q    = lane >> 4;     // k-group
  const int grow = (blockIdx.x << 7) + (wave << 4) + r16;

  const float nvx = -vec[grow * 3 + 0];
  const float nvy = -vec[grow * 3 + 1];
  const float nvz = -vec[grow * 3 + 2];

  f32x4 acc[4];
  #pragma unroll
  for (int nb = 0; nb < 4; ++nb) acc[nb] = (f32x4){0.f, 0.f, 0.f, 0.f};
  float rsum = 0.0f;

  const int swz_r = (lane & 7) << 4;   // (c&7)==(lane&7) for every nb block

  #pragma unroll
  for (int kt = 0; kt < 16; ++kt) {
    const int j0 = kt * 32 + q * 8;    // this lane's 8 consecutive sphere indices

    float sx[8], sy[8], sz[8];
    {
      float4 t;
      t = *reinterpret_cast<const float4*>(&slds[j0]);
      sx[0]=t.x; sx[1]=t.y; sx[2]=t.z; sx[3]=t.w;
      t = *reinterpret_cast<const float4*>(&slds[j0 + 4]);
      sx[4]=t.x; sx[5]=t.y; sx[6]=t.z; sx[7]=t.w;
      t = *reinterpret_cast<const float4*>(&slds[512 + j0]);
      sy[0]=t.x; sy[1]=t.y; sy[2]=t.z; sy[3]=t.w;
      t = *reinterpret_cast<const float4*>(&slds[512 + j0 + 4]);
      sy[4]=t.x; sy[5]=t.y; sy[6]=t.z; sy[7]=t.w;
      t = *reinterpret_cast<const float4*>(&slds[1024 + j0]);
      sz[0]=t.x; sz[1]=t.y; sz[2]=t.z; sz[3]=t.w;
      t = *reinterpret_cast<const float4*>(&slds[1024 + j0 + 4]);
      sz[4]=t.x; sz[5]=t.y; sz[6]=t.z; sz[7]=t.w;
    }

    float pr[8];
    #pragma unroll
    for (int e = 0; e < 8; ++e) {
      // u = 1 - dot  (3 fma; no clamp needed: exp2 underflows where series is loose)
      const float uu = fmaf(nvx, sx[e], fmaf(nvy, sy[e], fmaf(nvz, sz[e], 1.0f)));
      float P = fmaf(uu, 0.04444444f, 0.16666667f);
      P = fmaf(uu, P, 1.0f);
      pr[e] = fast_exp2(fmaf(uu * P, K1, K2));
      rsum += pr[e];
    }

    union { bf16x8 v; unsigned u32[4]; } af;
    #pragma unroll
    for (int p = 0; p < 4; ++p) {
      unsigned r;
      asm("v_cvt_pk_bf16_f32 %0, %1, %2" : "=v"(r) : "v"(pr[2 * p]), "v"(pr[2 * p + 1]));
      af.u32[p] = r;
    }

    const int kbyte = j0 << 1;
    #pragma unroll
    for (int nb = 0; nb < 4; ++nb) {
      const bf16x8 bf = *reinterpret_cast<const bf16x8*>(
          wlds + (((((nb << 4) + r16) << 10) + kbyte) ^ swz_r));
      acc[nb] = __builtin_amdgcn_mfma_f32_16x16x32_bf16(af.v, bf, acc[nb], 0, 0, 0);
    }
  }

  // full row-sum: lanes {l, l^16, l^32, l^48} share a row
  rsum += __shfl_xor(rsum, 16);
  rsum += __shfl_xor(rsum, 32);

  // C/D layout: col = lane&15, row = (lane>>4)*4 + reg
  #pragma unroll
  for (int reg = 0; reg < 4; ++reg) {
    const int orow = (q << 2) + reg;
    const float rs   = __shfl(rsum, orow);        // lane 'orow' holds row orow's sum
    const float rinv = 1.0f / (rs + 1e-8f);
    const int base = (((blockIdx.x << 7) + (wave << 4) + orow) << 6) + r16;
    out[base +  0] = acc[0][reg] * rinv;
    out[base + 16] = acc[1][reg] * rinv;
    out[base + 32] = acc[2][reg] * rinv;
    out[base + 48] = acc[3][reg] * rinv;
  }
}

extern "C" void kernel_launch(void* const* d_in, const int* in_sizes, int n_in,
                              void* d_out, int out_size, void* d_ws, size_t ws_size,
                              hipStream_t stream) {
  const float* vec = (const float*)d_in[0];
  const float* sph = (const float*)d_in[1];
  const float* wts = (const float*)d_in[2];
  const float* sig = (const float*)d_in[3];
  float* out = (float*)d_out;
  const int n      = in_sizes[0] / 3;   // 262144
  const int blocks = n >> 7;            // 128 rows per block
  hipLaunchKernelGGL(sph_enc_kernel, dim3(blocks), dim3(512), 0, stream,
                     vec, sph, wts, sig, out);
}

// Round 4
// 54.467 us; speedup vs baseline: 1.9627x; 1.1379x over previous
//
#include <hip/hip_runtime.h>

typedef short bf16x8 __attribute__((ext_vector_type(8)));
typedef float f32x4  __attribute__((ext_vector_type(4)));
typedef float f32x2  __attribute__((ext_vector_type(2)));

__device__ __forceinline__ unsigned short f2bf_rne(float x) {
  union { float f; unsigned u; } a; a.f = x;
  unsigned r = a.u + 0x7fffu + ((a.u >> 16) & 1u);   // round-to-nearest-even
  return (unsigned short)(r >> 16);
}

__device__ __forceinline__ float fast_exp2(float x) {
#if __has_builtin(__builtin_amdgcn_exp2f)
  return __builtin_amdgcn_exp2f(x);
#else
  float r; asm("v_exp_f32 %0, %1" : "=v"(r) : "v"(x)); return r;
#endif
}

__device__ __forceinline__ unsigned cvt_pk_bf16(float a, float b) {
  unsigned r; asm("v_cvt_pk_bf16_f32 %0, %1, %2" : "=v"(r) : "v"(a), "v"(b)); return r;
}

// vec:[N][3] f32, sph:[3][512] f32, wts:[512][64] f32, sigma:[1] f32 -> out:[N][64] f32
__global__ __launch_bounds__(1024, 8) void sph_enc_kernel(
    const float* __restrict__ vec,
    const float* __restrict__ sph,
    const float* __restrict__ wts,
    const float* __restrict__ sigp,
    float* __restrict__ out)
{
  // WT[c][k] bf16, c-major (1KB rows), XOR-swizzled byte^=(c&7)<<4.
  __shared__ __align__(16) unsigned char wlds[64 * 512 * 2];   // 64 KB
  __shared__ __align__(16) float slds[3 * 512];                // 6 KB

  const int tid  = threadIdx.x;
  const int lane = tid & 63;
  const int wave = tid >> 6;          // 0..15

  // ---- stage sphere_pos (1536 f32; 1024 threads -> grid-stride, covers all) ----
  for (int i = tid; i < 1536; i += 1024) slds[i] = sph[i];

  // ---- stage weights: [512][64] f32 -> bf16 WT[c][k] swizzled ----
  {
    const int c    = tid & 63;
    const int kgrp = tid >> 6;                    // 0..15
    const int swz  = (c & 7) << 4;
    #pragma unroll
    for (int pass = 0; pass < 4; ++pass) {
      const int k0 = pass * 128 + (kgrp << 3);
      unsigned pk[4];
      #pragma unroll
      for (int i = 0; i < 4; ++i) {
        const unsigned lo = f2bf_rne(wts[(k0 + 2 * i)     * 64 + c]);
        const unsigned hi = f2bf_rne(wts[(k0 + 2 * i + 1) * 64 + c]);
        pk[i] = lo | (hi << 16);
      }
      *reinterpret_cast<uint4*>(wlds + (((c << 10) + (k0 << 1)) ^ swz)) =
          make_uint4(pk[0], pk[1], pk[2], pk[3]);
    }
  }
  __syncthreads();

  const float sigma = sigp[0];
  // p = exp2( (u*P(u)) * K1 + K2 ),  u = 1 - cos
  const float K1 = -1.44269504f / (sigma * sigma);
  const float K2 = -__log2f(2.50662827463f * sigma);
  const f32x2 K1v  = {K1, K1};
  const f32x2 K2v  = {K2, K2};
  const f32x2 one2 = {1.0f, 1.0f};
  const f32x2 Ca   = {0.04444444f, 0.04444444f};
  const f32x2 Cb   = {0.16666667f, 0.16666667f};

  const int r16  = lane & 15;     // MFMA A-row / D-col index
  const int q    = lane >> 4;     // k-group
  const int grow = (blockIdx.x << 8) + (wave << 4) + r16;

  const float vx = -vec[grow * 3 + 0];
  const float vy = -vec[grow * 3 + 1];
  const float vz = -vec[grow * 3 + 2];
  const f32x2 nvx2 = {vx, vx};
  const f32x2 nvy2 = {vy, vy};
  const f32x2 nvz2 = {vz, vz};

  f32x4 acc[4];
  #pragma unroll
  for (int nb = 0; nb < 4; ++nb) acc[nb] = (f32x4){0.f, 0.f, 0.f, 0.f};
  float rsum = 0.0f;

  const int swz_r = (lane & 7) << 4;   // (c&7)==(lane&7) for every nb block

  #pragma unroll
  for (int kt = 0; kt < 16; ++kt) {
    const int j0 = kt * 32 + q * 8;    // this lane's 8 consecutive sphere indices
    union { bf16x8 v; unsigned u32[4]; } af;

    #pragma unroll
    for (int h = 0; h < 2; ++h) {      // 4 evals per half -> lower reg pressure
      const int jh = j0 + 4 * h;
      const f32x4 X = *reinterpret_cast<const f32x4*>(&slds[jh]);
      const f32x4 Y = *reinterpret_cast<const f32x4*>(&slds[512 + jh]);
      const f32x4 Z = *reinterpret_cast<const f32x4*>(&slds[1024 + jh]);
      #pragma unroll
      for (int p = 0; p < 2; ++p) {    // packed pair of evals (VOP3P)
        const f32x2 sx = {X[2 * p], X[2 * p + 1]};
        const f32x2 sy = {Y[2 * p], Y[2 * p + 1]};
        const f32x2 sz = {Z[2 * p], Z[2 * p + 1]};
        f32x2 u = __builtin_elementwise_fma(nvz2, sz, one2);
        u = __builtin_elementwise_fma(nvy2, sy, u);
        u = __builtin_elementwise_fma(nvx2, sx, u);
        f32x2 P = __builtin_elementwise_fma(u, Ca, Cb);
        P = __builtin_elementwise_fma(u, P, one2);
        const f32x2 arg = __builtin_elementwise_fma(u * P, K1v, K2v);
        const float p0 = fast_exp2(arg.x);
        const float p1 = fast_exp2(arg.y);
        rsum += p0;
        rsum += p1;
        af.u32[h * 2 + p] = cvt_pk_bf16(p0, p1);
      }
    }

    const int kbyte = j0 << 1;
    #pragma unroll
    for (int nb = 0; nb < 4; ++nb) {
      const bf16x8 bf = *reinterpret_cast<const bf16x8*>(
          wlds + (((((nb << 4) + r16) << 10) + kbyte) ^ swz_r));
      acc[nb] = __builtin_amdgcn_mfma_f32_16x16x32_bf16(af.v, bf, acc[nb], 0, 0, 0);
    }
  }

  // full row-sum: lanes {l, l^16, l^32, l^48} share a row
  rsum += __shfl_xor(rsum, 16);
  rsum += __shfl_xor(rsum, 32);

  // C/D layout: col = lane&15, row = (lane>>4)*4 + reg
  #pragma unroll
  for (int reg = 0; reg < 4; ++reg) {
    const int orow = (q << 2) + reg;
    const float rs   = __shfl(rsum, orow);        // lane 'orow' holds row orow's sum
    const float rinv = 1.0f / (rs + 1e-8f);
    const int base = (((blockIdx.x << 8) + (wave << 4) + orow) << 6) + r16;
    out[base +  0] = acc[0][reg] * rinv;
    out[base + 16] = acc[1][reg] * rinv;
    out[base + 32] = acc[2][reg] * rinv;
    out[base + 48] = acc[3][reg] * rinv;
  }
}

extern "C" void kernel_launch(void* const* d_in, const int* in_sizes, int n_in,
                              void* d_out, int out_size, void* d_ws, size_t ws_size,
                              hipStream_t stream) {
  const float* vec = (const float*)d_in[0];
  const float* sph = (const float*)d_in[1];
  const float* wts = (const float*)d_in[2];
  const float* sig = (const float*)d_in[3];
  float* out = (float*)d_out;
  const int n      = in_sizes[0] / 3;   // 262144
  const int blocks = n >> 8;            // 256 rows per block
  hipLaunchKernelGGL(sph_enc_kernel, dim3(blocks), dim3(1024), 0, stream,
                     vec, sph, wts, sig, out);
}

// Round 6
// 51.840 us; speedup vs baseline: 2.0621x; 1.0507x over previous
//
#include <hip/hip_runtime.h>

typedef short bf16x8 __attribute__((ext_vector_type(8)));
typedef float f32x4  __attribute__((ext_vector_type(4)));

__device__ __forceinline__ unsigned short f2bf_rne(float x) {
  union { float f; unsigned u; } a; a.f = x;
  unsigned r = a.u + 0x7fffu + ((a.u >> 16) & 1u);   // round-to-nearest-even
  return (unsigned short)(r >> 16);
}

__device__ __forceinline__ float fast_exp2(float x) {
#if __has_builtin(__builtin_amdgcn_exp2f)
  return __builtin_amdgcn_exp2f(x);
#else
  float r; asm("v_exp_f32 %0, %1" : "=v"(r) : "v"(x)); return r;
#endif
}

__device__ __forceinline__ unsigned cvt_pk_bf16(float a, float b) {
  unsigned r; asm("v_cvt_pk_bf16_f32 %0, %1, %2" : "=v"(r) : "v"(a), "v"(b)); return r;
}

// vec:[N][3] f32, sph:[3][512] f32, wts:[512][64] f32, sigma:[1] f32 -> out:[N][64] f32
__global__ __launch_bounds__(1024, 8) void sph_enc_kernel(
    const float* __restrict__ vec,
    const float* __restrict__ sph,
    const float* __restrict__ wts,
    const float* __restrict__ sigp,
    float* __restrict__ out)
{
  // WT[c][k] bf16, c-major (1KB rows), XOR-swizzled byte^=(c&7)<<4.
  __shared__ __align__(16) unsigned char wlds[64 * 512 * 2];   // 64 KB
  __shared__ __align__(16) float slds[3 * 512];                // 6 KB

  const int tid  = threadIdx.x;
  const int lane = tid & 63;
  const int wave = tid >> 6;          // 0..15

  // ---- stage sphere_pos (1536 f32; stride loop covers all with 1024 thr) ----
  for (int i = tid; i < 1536; i += 1024) slds[i] = sph[i];

  // ---- stage weights: [512][64] f32 -> bf16 WT[c][k] swizzled ----
  {
    const int c    = tid & 63;
    const int kgrp = tid >> 6;                    // 0..15
    const int swz  = (c & 7) << 4;
    #pragma unroll
    for (int pass = 0; pass < 4; ++pass) {
      const int k0 = pass * 128 + (kgrp << 3);
      unsigned pk[4];
      #pragma unroll
      for (int i = 0; i < 4; ++i) {
        const unsigned lo = f2bf_rne(wts[(k0 + 2 * i)     * 64 + c]);
        const unsigned hi = f2bf_rne(wts[(k0 + 2 * i + 1) * 64 + c]);
        pk[i] = lo | (hi << 16);
      }
      *reinterpret_cast<uint4*>(wlds + (((c << 10) + (k0 << 1)) ^ swz)) =
          make_uint4(pk[0], pk[1], pk[2], pk[3]);
    }
  }
  __syncthreads();

  const float sigma = sigp[0];
  // arg = u*(u*C2 + C1) + K2 ; p = exp2(arg) ; u = 1 - cos
  // (2-term series for acos^2: exact to <0.35% wherever prob is non-negligible)
  const float C1 = -1.44269504f / (sigma * sigma);   // K1
  const float C2 = C1 * 0.16666667f;                 // K1/6
  const float K2 = -__log2f(2.50662827463f * sigma);

  const int r16  = lane & 15;     // MFMA A-row / D-col index
  const int q    = lane >> 4;     // k-group
  const int grow = (blockIdx.x << 8) + (wave << 4) + r16;

  const float nvx = -vec[grow * 3 + 0];
  const float nvy = -vec[grow * 3 + 1];
  const float nvz = -vec[grow * 3 + 2];

  f32x4 acc[4];
  #pragma unroll
  for (int nb = 0; nb < 4; ++nb) acc[nb] = (f32x4){0.f, 0.f, 0.f, 0.f};
  float rsa = 0.0f, rsb = 0.0f;   // two accumulators to break the add chain

  const int swz_r = (lane & 7) << 4;   // (c&7)==(lane&7) for every nb block

  #pragma unroll
  for (int kt = 0; kt < 16; ++kt) {
    const int j0 = kt * 32 + q * 8;    // this lane's 8 consecutive sphere indices
    union { bf16x8 v; unsigned u32[4]; } af;

    #pragma unroll
    for (int h = 0; h < 2; ++h) {      // 4 evals per half
      const int jh = j0 + 4 * h;
      const f32x4 X = *reinterpret_cast<const f32x4*>(&slds[jh]);
      const f32x4 Y = *reinterpret_cast<const f32x4*>(&slds[512 + jh]);
      const f32x4 Z = *reinterpret_cast<const f32x4*>(&slds[1024 + jh]);
      float p[4];
      #pragma unroll
      for (int e = 0; e < 4; ++e) {
        const float u = fmaf(nvx, X[e], fmaf(nvy, Y[e], fmaf(nvz, Z[e], 1.0f)));
        p[e] = fast_exp2(fmaf(u, fmaf(u, C2, C1), K2));
      }
      rsa += p[0] + p[2];
      rsb += p[1] + p[3];
      af.u32[2 * h]     = cvt_pk_bf16(p[0], p[1]);
      af.u32[2 * h + 1] = cvt_pk_bf16(p[2], p[3]);
    }

    const int kbyte = j0 << 1;
    #pragma unroll
    for (int nb = 0; nb < 4; ++nb) {
      const bf16x8 bf = *reinterpret_cast<const bf16x8*>(
          wlds + (((((nb << 4) + r16) << 10) + kbyte) ^ swz_r));
      acc[nb] = __builtin_amdgcn_mfma_f32_16x16x32_bf16(af.v, bf, acc[nb], 0, 0, 0);
    }
  }

  float rsum = rsa + rsb;
  // full row-sum: lanes {l, l^16, l^32, l^48} share a row
  rsum += __shfl_xor(rsum, 16);
  rsum += __shfl_xor(rsum, 32);

  // C/D layout: col = lane&15, row = (lane>>4)*4 + reg
  #pragma unroll
  for (int reg = 0; reg < 4; ++reg) {
    const int orow = (q << 2) + reg;
    const float rs   = __shfl(rsum, orow);        // lane 'orow' holds row orow's sum
    const float rinv = 1.0f / (rs + 1e-8f);
    const int base = (((blockIdx.x << 8) + (wave << 4) + orow) << 6) + r16;
    out[base +  0] = acc[0][reg] * rinv;
    out[base + 16] = acc[1][reg] * rinv;
    out[base + 32] = acc[2][reg] * rinv;
    out[base + 48] = acc[3][reg] * rinv;
  }
}

extern "C" void kernel_launch(void* const* d_in, const int* in_sizes, int n_in,
                              void* d_out, int out_size, void* d_ws, size_t ws_size,
                              hipStream_t stream) {
  const float* vec = (const float*)d_in[0];
  const float* sph = (const float*)d_in[1];
  const float* wts = (const float*)d_in[2];
  const float* sig = (const float*)d_in[3];
  float* out = (float*)d_out;
  const int n      = in_sizes[0] / 3;   // 262144
  const int blocks = n >> 8;            // 256 rows per block
  hipLaunchKernelGGL(sph_enc_kernel, dim3(blocks), dim3(1024), 0, stream,
                     vec, sph, wts, sig, out);
}

// Round 8
// 48.957 us; speedup vs baseline: 2.1836x; 1.0589x over previous
//
#include <hip/hip_runtime.h>

typedef short bf16x8 __attribute__((ext_vector_type(8)));
typedef float f32x4  __attribute__((ext_vector_type(4)));

__device__ __forceinline__ unsigned short f2bf_rne(float x) {
  union { float f; unsigned u; } a; a.f = x;
  unsigned r = a.u + 0x7fffu + ((a.u >> 16) & 1u);   // round-to-nearest-even
  return (unsigned short)(r >> 16);
}

__device__ __forceinline__ float fast_exp2(float x) {
#if __has_builtin(__builtin_amdgcn_exp2f)
  return __builtin_amdgcn_exp2f(x);
#else
  float r; asm("v_exp_f32 %0, %1" : "=v"(r) : "v"(x)); return r;
#endif
}

__device__ __forceinline__ unsigned cvt_pk_bf16(float a, float b) {
  unsigned r; asm("v_cvt_pk_bf16_f32 %0, %1, %2" : "=v"(r) : "v"(a), "v"(b)); return r;
}

// vec:[N][3] f32, sph:[3][512] f32, wts:[512][64] f32, sigma:[1] f32 -> out:[N][64] f32
// 1024 thr/block (16 waves). Each wave owns rows {base..base+15} and {base+256..base+271}
// (two register-blocked row-tiles sharing all LDS reads). 512 rows/block.
__global__ __launch_bounds__(1024, 4) void sph_enc_kernel(
    const float* __restrict__ vec,
    const float* __restrict__ sph,
    const float* __restrict__ wts,
    const float* __restrict__ sigp,
    float* __restrict__ out)
{
  // WT[c][k] bf16, c-major (1KB rows), XOR-swizzled byte^=(c&7)<<4.
  __shared__ __align__(16) unsigned char wlds[64 * 512 * 2];   // 64 KB
  __shared__ __align__(16) float slds[3 * 512];                // 6 KB

  const int tid  = threadIdx.x;
  const int lane = tid & 63;
  const int wave = tid >> 6;          // 0..15

  // ---- stage sphere_pos (1536 f32; stride loop covers all with 1024 thr) ----
  for (int i = tid; i < 1536; i += 1024) slds[i] = sph[i];

  // ---- stage weights: [512][64] f32 -> bf16 WT[c][k] swizzled (round-6 verbatim) ----
  {
    const int c    = tid & 63;
    const int kgrp = tid >> 6;                    // 0..15
    const int swz  = (c & 7) << 4;
    #pragma unroll
    for (int pass = 0; pass < 4; ++pass) {
      const int k0 = pass * 128 + (kgrp << 3);
      unsigned pk[4];
      #pragma unroll
      for (int i = 0; i < 4; ++i) {
        const unsigned lo = f2bf_rne(wts[(k0 + 2 * i)     * 64 + c]);
        const unsigned hi = f2bf_rne(wts[(k0 + 2 * i + 1) * 64 + c]);
        pk[i] = lo | (hi << 16);
      }
      *reinterpret_cast<uint4*>(wlds + (((c << 10) + (k0 << 1)) ^ swz)) =
          make_uint4(pk[0], pk[1], pk[2], pk[3]);
    }
  }
  __syncthreads();

  const float sigma = sigp[0];
  // arg = u*(u*C2 + C1) + K2 ; p = exp2(arg) ; u = 1 - cos
  const float C1 = -1.44269504f / (sigma * sigma);
  const float C2 = C1 * 0.16666667f;
  const float K2 = -__log2f(2.50662827463f * sigma);

  const int r16  = lane & 15;     // MFMA A-row / D-col index
  const int q    = lane >> 4;     // k-group
  const int row0 = (blockIdx.x << 9) + (wave << 4) + r16;   // tile-0 sample row
  const int row1 = row0 + 256;                              // tile-1 sample row

  const float nvx0 = -vec[row0 * 3 + 0];
  const float nvy0 = -vec[row0 * 3 + 1];
  const float nvz0 = -vec[row0 * 3 + 2];
  const float nvx1 = -vec[row1 * 3 + 0];
  const float nvy1 = -vec[row1 * 3 + 1];
  const float nvz1 = -vec[row1 * 3 + 2];

  f32x4 acc0[4], acc1[4];
  #pragma unroll
  for (int nb = 0; nb < 4; ++nb) {
    acc0[nb] = (f32x4){0.f, 0.f, 0.f, 0.f};
    acc1[nb] = (f32x4){0.f, 0.f, 0.f, 0.f};
  }
  float rsa0 = 0.f, rsb0 = 0.f, rsa1 = 0.f, rsb1 = 0.f;

  const int swz_r = (lane & 7) << 4;   // (c&7)==(lane&7) for every nb block

  #pragma unroll
  for (int kt = 0; kt < 16; ++kt) {
    const int j0 = kt * 32 + q * 8;    // this lane's 8 consecutive sphere indices
    union { bf16x8 v; unsigned u32[4]; } af0, af1;

    #pragma unroll
    for (int h = 0; h < 2; ++h) {      // 4 j's per half; reads shared by both tiles
      const int jh = j0 + 4 * h;
      const f32x4 X = *reinterpret_cast<const f32x4*>(&slds[jh]);
      const f32x4 Y = *reinterpret_cast<const f32x4*>(&slds[512 + jh]);
      const f32x4 Z = *reinterpret_cast<const f32x4*>(&slds[1024 + jh]);
      float p[4];
      #pragma unroll
      for (int e = 0; e < 4; ++e) {
        const float u = fmaf(nvx0, X[e], fmaf(nvy0, Y[e], fmaf(nvz0, Z[e], 1.0f)));
        p[e] = fast_exp2(fmaf(u, fmaf(u, C2, C1), K2));
      }
      rsa0 += p[0] + p[2];
      rsb0 += p[1] + p[3];
      af0.u32[2 * h]     = cvt_pk_bf16(p[0], p[1]);
      af0.u32[2 * h + 1] = cvt_pk_bf16(p[2], p[3]);
      #pragma unroll
      for (int e = 0; e < 4; ++e) {
        const float u = fmaf(nvx1, X[e], fmaf(nvy1, Y[e], fmaf(nvz1, Z[e], 1.0f)));
        p[e] = fast_exp2(fmaf(u, fmaf(u, C2, C1), K2));
      }
      rsa1 += p[0] + p[2];
      rsb1 += p[1] + p[3];
      af1.u32[2 * h]     = cvt_pk_bf16(p[0], p[1]);
      af1.u32[2 * h + 1] = cvt_pk_bf16(p[2], p[3]);
    }

    const int kbyte = j0 << 1;
    #pragma unroll
    for (int nb = 0; nb < 4; ++nb) {   // one B read feeds both row-tiles
      const bf16x8 bf = *reinterpret_cast<const bf16x8*>(
          wlds + (((((nb << 4) + r16) << 10) + kbyte) ^ swz_r));
      acc0[nb] = __builtin_amdgcn_mfma_f32_16x16x32_bf16(af0.v, bf, acc0[nb], 0, 0, 0);
      acc1[nb] = __builtin_amdgcn_mfma_f32_16x16x32_bf16(af1.v, bf, acc1[nb], 0, 0, 0);
    }
  }

  // row sums: lanes {l, l^16, l^32, l^48} share a row (per row-tile)
  float rsum0 = rsa0 + rsb0;
  float rsum1 = rsa1 + rsb1;
  rsum0 += __shfl_xor(rsum0, 16);
  rsum0 += __shfl_xor(rsum0, 32);
  rsum1 += __shfl_xor(rsum1, 16);
  rsum1 += __shfl_xor(rsum1, 32);

  // C/D layout: col = lane&15, row = (lane>>4)*4 + reg
  const int obase = (blockIdx.x << 9) + (wave << 4);
  #pragma unroll
  for (int reg = 0; reg < 4; ++reg) {
    const int orow = (q << 2) + reg;
    const float rinv0 = 1.0f / (__shfl(rsum0, orow) + 1e-8f);
    const float rinv1 = 1.0f / (__shfl(rsum1, orow) + 1e-8f);
    const int b0 = ((obase + orow) << 6) + r16;
    const int b1 = ((obase + 256 + orow) << 6) + r16;
    out[b0 +  0] = acc0[0][reg] * rinv0;
    out[b0 + 16] = acc0[1][reg] * rinv0;
    out[b0 + 32] = acc0[2][reg] * rinv0;
    out[b0 + 48] = acc0[3][reg] * rinv0;
    out[b1 +  0] = acc1[0][reg] * rinv1;
    out[b1 + 16] = acc1[1][reg] * rinv1;
    out[b1 + 32] = acc1[2][reg] * rinv1;
    out[b1 + 48] = acc1[3][reg] * rinv1;
  }
}

extern "C" void kernel_launch(void* const* d_in, const int* in_sizes, int n_in,
                              void* d_out, int out_size, void* d_ws, size_t ws_size,
                              hipStream_t stream) {
  const float* vec = (const float*)d_in[0];
  const float* sph = (const float*)d_in[1];
  const float* wts = (const float*)d_in[2];
  const float* sig = (const float*)d_in[3];
  float* out = (float*)d_out;
  const int n      = in_sizes[0] / 3;   // 262144
  const int blocks = n >> 9;            // 512 rows per block (16 waves x 2 tiles x 16)
  hipLaunchKernelGGL(sph_enc_kernel, dim3(blocks), dim3(1024), 0, stream,
                     vec, sph, wts, sig, out);
}